// Round 7
// baseline (423.257 us; speedup 1.0000x reference)
//
#include <hip/hip_runtime.h>
#include <math.h>

// Problem constants (fixed by the reference)
#define NND 50000   // nodes
#define NED 600000  // edges
#define CD  128     // channels (in = hid = 128)
#define NG  64      // graphs
#define NBLK 196    // ceil(NND/256) scan blocks
#define GROWS 64    // rows per fused block
#define LSTR 136    // LDS row stride in bf16 (128 + 8 pad -> bank-balanced b128)

typedef short s8v  __attribute__((ext_vector_type(8)));   // 8 bf16 (raw bits) = 4 VGPRs
typedef float f4v  __attribute__((ext_vector_type(4)));   // MFMA accumulator
typedef unsigned short u16x4 __attribute__((ext_vector_type(4)));
typedef unsigned short u16x8 __attribute__((ext_vector_type(8)));

static __device__ __forceinline__ unsigned short f2bf(float f) {
  union { float f; unsigned u; } v; v.f = f;
  unsigned r = v.u + 0x7fffu + ((v.u >> 16) & 1u);   // round-to-nearest-even
  return (unsigned short)(r >> 16);
}
static __device__ __forceinline__ float bf2f(unsigned short h) {
  union { unsigned u; float f; } v; v.u = ((unsigned)h) << 16; return v.f;
}

// ---- int degree count (CSR) ----
__global__ void counti_k(const int* __restrict__ idx, int* __restrict__ cnt, int n) {
  int t = blockIdx.x * blockDim.x + threadIdx.x;
  if (t < n) atomicAdd(&cnt[idx[t]], 1);
}

// ---- graph boundaries via binary search in SORTED batch: gb[g] = lower_bound(g) ----
__global__ void bounds_k(const int* __restrict__ batch, int* __restrict__ gb) {
  int g = threadIdx.x;
  if (g > NG) return;
  int lo = 0, hi = NND;
  while (lo < hi) {
    int mid = (lo + hi) >> 1;
    if (batch[mid] < g) lo = mid + 1; else hi = mid;
  }
  gb[g] = lo;
}

// ---- 3-stage grid scan of cnt[NND] -> offs (exclusive), cur, offs[NND]=total ----
__global__ __launch_bounds__(256) void bsum_k(const int* __restrict__ cnt,
                                              int* __restrict__ bsum) {
  __shared__ int s[256];
  int i = blockIdx.x * 256 + threadIdx.x;
  s[threadIdx.x] = (i < NND) ? cnt[i] : 0;
  __syncthreads();
  for (int off = 128; off > 0; off >>= 1) {
    if (threadIdx.x < off) s[threadIdx.x] += s[threadIdx.x + off];
    __syncthreads();
  }
  if (threadIdx.x == 0) bsum[blockIdx.x] = s[0];
}

__global__ __launch_bounds__(256) void bscan_k(const int* __restrict__ bsum,
                                               int* __restrict__ boff,
                                               int* __restrict__ offs) {
  __shared__ int s[256];
  int t = threadIdx.x;
  s[t] = (t < NBLK) ? bsum[t] : 0;
  __syncthreads();
  for (int off = 1; off < 256; off <<= 1) {   // inclusive Hillis-Steele
    int v = (t >= off) ? s[t - off] : 0;
    __syncthreads();
    s[t] += v;
    __syncthreads();
  }
  if (t < NBLK) boff[t] = (t == 0) ? 0 : s[t - 1];
  if (t == NBLK - 1) offs[NND] = s[t];        // grand total
}

__global__ __launch_bounds__(256) void escan_k(const int* __restrict__ cnt,
                                               const int* __restrict__ boff,
                                               int* __restrict__ offs,
                                               int* __restrict__ cur) {
  __shared__ int s[256];
  int i = blockIdx.x * 256 + threadIdx.x;
  int t = threadIdx.x;
  int v = (i < NND) ? cnt[i] : 0;
  s[t] = v;
  __syncthreads();
  for (int off = 1; off < 256; off <<= 1) {   // inclusive Hillis-Steele
    int u = (t >= off) ? s[t - off] : 0;
    __syncthreads();
    s[t] += u;
    __syncthreads();
  }
  if (i < NND) {
    int excl = s[t] - v + boff[blockIdx.x];   // inclusive - self = exclusive
    offs[i] = excl;
    cur[i]  = excl;
  }
}

// ---- CSR fill: csr[pos] = src for edges grouped by dst ----
__global__ void fill_k(const int* __restrict__ src, const int* __restrict__ dst,
                       int* __restrict__ cur, int* __restrict__ csr) {
  int e = blockIdx.x * blockDim.x + threadIdx.x;
  if (e >= NED) return;
  int d = dst[e];
  int pos = atomicAdd(&cur[d], 1);
  csr[pos] = src[e];
}

// ---- fp32 -> bf16 conversion (layer-0 input) ----
__global__ void cvt_k(const float* __restrict__ in, unsigned short* __restrict__ out) {
  int t = blockIdx.x * blockDim.x + threadIdx.x;   // one float4 chunk; NND*32 total
  if (t >= NND * 32) return;
  float4 v = reinterpret_cast<const float4*>(in)[t];
  u16x4 o;
  o.x = f2bf(v.x); o.y = f2bf(v.y); o.z = f2bf(v.z); o.w = f2bf(v.w);
  reinterpret_cast<u16x4*>(out)[t] = o;
}

// ---- all 8 weight transposes+converts in ONE launch: WT[n*128+k]=bf16(W[k*128+n]) ----
struct WPtrs { const float* w[8]; unsigned short* wt[8]; };
__global__ void wcvt8_k(WPtrs p) {
  int t = blockIdx.x * blockDim.x + threadIdx.x;   // 8 * 16384 total
  if (t >= 8 * CD * CD) return;
  int m = t >> 14, r = t & (CD * CD - 1);
  int n = r >> 7, k = r & 127;
  p.wt[m][r] = f2bf(p.w[m][k * CD + n]);
}

// ---- FUSED SAGE layer: gather-mean (CSR) -> LDS, then
//      h = relu(agg @ Wl + x @ Wr + bias) via MFMA.
// Block = 256 threads, 64 node rows.
// Phase 1: 16 teams x 16 lanes; lane owns 8 channels (16B u16x8 gathers,
//          4-edge unroll); mean written bf16 to LDS (stride LSTR, bank-balanced).
// Phase 2: wave w owns cols [w*32,w*32+32); B frags (Wl+Wr) register-resident;
//          A_agg from LDS (ds_read_b128), A_root from global; both products in
//          one accumulator. Layers 0-2 write hb (bf16); layer 3 hf (fp32).
// MFMA 16x16x32 bf16; A: m=lane&15, k=kk*32+quad*8+j; B from WT[n][k]: n=lane&15;
// C/D: col=lane&15, row=quad*4+r (m89/m91-verified).
__global__ __launch_bounds__(256) void fuse_k(
    const unsigned short* __restrict__ xb, const int* __restrict__ csr,
    const int* __restrict__ offs,
    const unsigned short* __restrict__ WlT, const unsigned short* __restrict__ WrT,
    const float* __restrict__ bias, float* __restrict__ hf,
    unsigned short* __restrict__ hb) {
  __shared__ unsigned short abuf[GROWS * LSTR];

  const int tid  = threadIdx.x;
  const int wave = tid >> 6;
  const int lane = tid & 63;
  const int quad = lane >> 4;
  const int l16  = lane & 15;
  const int rbase = blockIdx.x * GROWS;

  // Phase 0: B fragments -> registers (issued early; overlap with gather)
  s8v bL[2][4], bR[2][4];
#pragma unroll
  for (int nt = 0; nt < 2; ++nt) {
    const int n = wave * 32 + nt * 16 + l16;
#pragma unroll
    for (int kk = 0; kk < 4; ++kk) {
      size_t woff = (size_t)n * CD + kk * 32 + quad * 8;
      bL[nt][kk] = *reinterpret_cast<const s8v*>(WlT + woff);
      bR[nt][kk] = *reinterpret_cast<const s8v*>(WrT + woff);
    }
  }
  const float bv0 = bias[wave * 32 + l16];
  const float bv1 = bias[wave * 32 + 16 + l16];

  // Phase 1: gather-mean into LDS
  const int team = tid >> 4;       // 16 teams
  const int tl   = tid & 15;       // lane in team; owns channels [tl*8, tl*8+8)
  const unsigned short* gbase = xb + tl * 8;
#pragma unroll
  for (int i = 0; i < GROWS / 16; ++i) {
    const int rl  = team + 16 * i;     // local row
    const int row = rbase + rl;
    if (row < NND) {
      const int e0 = offs[row], e1 = offs[row + 1];
      float a[8] = {};
      int e = e0;
      for (; e + 4 <= e1; e += 4) {
        int s0 = csr[e], s1 = csr[e + 1], s2 = csr[e + 2], s3 = csr[e + 3];
        u16x8 v0 = *reinterpret_cast<const u16x8*>(gbase + (size_t)s0 * CD);
        u16x8 v1 = *reinterpret_cast<const u16x8*>(gbase + (size_t)s1 * CD);
        u16x8 v2 = *reinterpret_cast<const u16x8*>(gbase + (size_t)s2 * CD);
        u16x8 v3 = *reinterpret_cast<const u16x8*>(gbase + (size_t)s3 * CD);
#pragma unroll
        for (int j = 0; j < 8; ++j)
          a[j] += bf2f(v0[j]) + bf2f(v1[j]) + bf2f(v2[j]) + bf2f(v3[j]);
      }
      for (; e < e1; ++e) {
        u16x8 v0 = *reinterpret_cast<const u16x8*>(gbase + (size_t)csr[e] * CD);
#pragma unroll
        for (int j = 0; j < 8; ++j) a[j] += bf2f(v0[j]);
      }
      const float invd = 1.0f / fmaxf((float)(e1 - e0), 1.0f);
      u16x8 o;
#pragma unroll
      for (int j = 0; j < 8; ++j) o[j] = f2bf(a[j] * invd);
      *reinterpret_cast<u16x8*>(abuf + rl * LSTR + tl * 8) = o;
    }
  }
  __syncthreads();

  // Phase 2: MFMA
#pragma unroll
  for (int rt = 0; rt < GROWS / 16; ++rt) {
    const int m0 = rbase + rt * 16;
    if (m0 >= NND) break;
    const int rowA  = m0 + l16;
    const int rowAc = rowA < NND ? rowA : NND - 1;
    s8v aA[4], aX[4];
#pragma unroll
    for (int kk = 0; kk < 4; ++kk) {
      aA[kk] = *reinterpret_cast<const s8v*>(abuf + (rt * 16 + l16) * LSTR +
                                             kk * 32 + quad * 8);
      aX[kk] = *reinterpret_cast<const s8v*>(xb + (size_t)rowAc * CD +
                                             kk * 32 + quad * 8);
    }
    f4v acc0 = {}, acc1 = {};
#pragma unroll
    for (int kk = 0; kk < 4; ++kk) {
      acc0 = __builtin_amdgcn_mfma_f32_16x16x32_bf16(aA[kk], bL[0][kk], acc0, 0, 0, 0);
      acc0 = __builtin_amdgcn_mfma_f32_16x16x32_bf16(aX[kk], bR[0][kk], acc0, 0, 0, 0);
      acc1 = __builtin_amdgcn_mfma_f32_16x16x32_bf16(aA[kk], bL[1][kk], acc1, 0, 0, 0);
      acc1 = __builtin_amdgcn_mfma_f32_16x16x32_bf16(aX[kk], bR[1][kk], acc1, 0, 0, 0);
    }
#pragma unroll
    for (int r = 0; r < 4; ++r) {
      const int row = m0 + quad * 4 + r;
      if (row < NND) {
        const int c0 = wave * 32 + l16;
        float v0 = fmaxf(acc0[r] + bv0, 0.0f);
        float v1 = fmaxf(acc1[r] + bv1, 0.0f);
        if (hb) {
          hb[(size_t)row * CD + c0]      = f2bf(v0);
          hb[(size_t)row * CD + c0 + 16] = f2bf(v1);
        }
        if (hf) {
          hf[(size_t)row * CD + c0]      = v0;
          hf[(size_t)row * CD + c0 + 16] = v1;
        }
      }
    }
  }
}

// ---- mean-pool: 32-row chunks, one thread per channel, boundary-flush atomics.
// batch is SORTED; common case = whole chunk inside one graph (branch-free sum). ----
__global__ __launch_bounds__(128) void pool3_k(const float* __restrict__ h,
                                               const int* __restrict__ batch,
                                               float* __restrict__ pooled) {
  const int c  = threadIdx.x;
  const int r0 = blockIdx.x * 32;
  const int rend = (r0 + 32 < NND) ? r0 + 32 : NND;
  const int g0 = batch[r0];
  const int g1 = batch[rend - 1];
  if (g0 == g1) {
    float acc = 0.f;
#pragma unroll
    for (int i = 0; i < 32; ++i) {
      int row = r0 + i;
      if (row < rend) acc += h[(size_t)row * CD + c];
    }
    atomicAdd(&pooled[g0 * CD + c], acc);
  } else {
    float acc = 0.f;
    int gcur = g0;
    for (int row = r0; row < rend; ++row) {
      int g = batch[row];
      if (g != gcur) {
        atomicAdd(&pooled[gcur * CD + c], acc);
        acc = 0.f; gcur = g;
      }
      acc += h[(size_t)row * CD + c];
    }
    atomicAdd(&pooled[gcur * CD + c], acc);
  }
}

// ---- classifier: out[g] = sigmoid(dot(pooled[g]/cnt, Wc) + bc) ----
__global__ void final_k(const float* __restrict__ pooled, const int* __restrict__ gb,
                        const float* __restrict__ Wc, const float* __restrict__ bc,
                        float* __restrict__ out) {
  int g = blockIdx.x;
  int lane = threadIdx.x;
  float part = pooled[g * CD + lane] * Wc[lane] +
               pooled[g * CD + 64 + lane] * Wc[64 + lane];
#pragma unroll
  for (int off = 32; off > 0; off >>= 1) part += __shfl_down(part, off, 64);
  if (lane == 0) {
    float cnt = (float)(gb[g + 1] - gb[g]);
    float z = part / fmaxf(cnt, 1.0f) + bc[0];
    out[g] = 1.0f / (1.0f + expf(-z));
  }
}

extern "C" void kernel_launch(void* const* d_in, const int* in_sizes, int n_in,
                              void* d_out, int out_size, void* d_ws, size_t ws_size,
                              hipStream_t stream) {
  const float* x   = (const float*)d_in[0];
  const int*   ei  = (const int*)d_in[1];
  const int*   src = ei;             // edge_index[0]
  const int*   dst = ei + NED;       // edge_index[1]
  // d_in[2] = edge_weight: unused by the reference
  const int*   batch = (const int*)d_in[3];
  const float* Wc = (const float*)d_in[16];
  const float* bc = (const float*)d_in[17];
  float* out = (float*)d_out;

  char* w = (char*)d_ws;
  auto alloc = [&](size_t bytes) {
    char* p = w; w += (bytes + 255) & ~(size_t)255; return p;
  };
  int* cnti = (int*)alloc(NND * 4);
  int* offs = (int*)alloc((NND + 1) * 4);
  int* cur  = (int*)alloc(NND * 4);
  int* csr  = (int*)alloc((size_t)NED * 4);
  int* gb   = (int*)alloc((NG + 1) * 4);
  int* bsum = (int*)alloc(256 * 4);
  int* boff = (int*)alloc(256 * 4);
  float* hA = (float*)alloc((size_t)NND * CD * 4);              // fp32 final-layer feats
  unsigned short* xb0 = (unsigned short*)alloc((size_t)NND * CD * 2);
  unsigned short* xb1 = (unsigned short*)alloc((size_t)NND * CD * 2);
  WPtrs wp;
  for (int i = 0; i < 4; ++i) {
    wp.w[2 * i]     = (const float*)d_in[4 + 3 * i];      // Wl{i+1}
    wp.w[2 * i + 1] = (const float*)d_in[5 + 3 * i];      // Wr{i+1}
  }
  for (int i = 0; i < 8; ++i) wp.wt[i] = (unsigned short*)alloc(CD * CD * 2);
  const float* bs[4] = {(const float*)d_in[6],  (const float*)d_in[9],
                        (const float*)d_in[12], (const float*)d_in[15]};
  float* pooled = (float*)alloc(NG * CD * 4);

  hipMemsetAsync(cnti, 0, NND * 4, stream);
  hipMemsetAsync(pooled, 0, NG * CD * 4, stream);

  // CSR build (per call; inputs are restored before every timed launch)
  counti_k<<<(NED + 255) / 256, 256, 0, stream>>>(dst, cnti, NED);
  bsum_k<<<NBLK, 256, 0, stream>>>(cnti, bsum);
  bscan_k<<<1, 256, 0, stream>>>(bsum, boff, offs);
  escan_k<<<NBLK, 256, 0, stream>>>(cnti, boff, offs, cur);
  fill_k<<<(NED + 255) / 256, 256, 0, stream>>>(src, dst, cur, csr);
  bounds_k<<<1, 128, 0, stream>>>(batch, gb);

  cvt_k<<<(NND * 32 + 255) / 256, 256, 0, stream>>>(x, xb0);
  wcvt8_k<<<(8 * CD * CD + 255) / 256, 256, 0, stream>>>(wp);

  unsigned short* xcur = xb0;
  unsigned short* xnxt = xb1;
  const int ggrid = (NND + GROWS - 1) / GROWS;
  for (int l = 0; l < 4; ++l) {
    if (l < 3) {
      fuse_k<<<ggrid, 256, 0, stream>>>(xcur, csr, offs, wp.wt[2 * l], wp.wt[2 * l + 1],
                                        bs[l], nullptr, xnxt);
    } else {
      fuse_k<<<ggrid, 256, 0, stream>>>(xcur, csr, offs, wp.wt[2 * l], wp.wt[2 * l + 1],
                                        bs[l], hA, nullptr);
    }
    unsigned short* t = xcur; xcur = xnxt; xnxt = t;
  }

  pool3_k<<<(NND + 31) / 32, 128, 0, stream>>>(hA, batch, pooled);
  final_k<<<NG, 64, 0, stream>>>(pooled, gb, Wc, bc, out);
}

// Round 8
// 393.387 us; speedup vs baseline: 1.0759x; 1.0759x over previous
//
#include <hip/hip_runtime.h>
#include <math.h>

// Problem constants (fixed by the reference)
#define NND 50000   // nodes
#define NED 600000  // edges
#define CD  128     // channels (in = hid = 128)
#define NG  64      // graphs
#define NBLK 196    // ceil(NND/256) scan blocks
#define GROWS 64    // rows per gemm block

typedef short s8v  __attribute__((ext_vector_type(8)));   // 8 bf16 (raw bits) = 4 VGPRs
typedef float f4v  __attribute__((ext_vector_type(4)));   // MFMA accumulator
typedef unsigned short u16x4 __attribute__((ext_vector_type(4)));
typedef unsigned short u16x8 __attribute__((ext_vector_type(8)));

static __device__ __forceinline__ unsigned short f2bf(float f) {
  union { float f; unsigned u; } v; v.f = f;
  unsigned r = v.u + 0x7fffu + ((v.u >> 16) & 1u);   // round-to-nearest-even
  return (unsigned short)(r >> 16);
}
static __device__ __forceinline__ float bf2f(unsigned short h) {
  union { unsigned u; float f; } v; v.u = ((unsigned)h) << 16; return v.f;
}

// ---- int degree count (CSR) ----
__global__ void counti_k(const int* __restrict__ idx, int* __restrict__ cnt, int n) {
  int t = blockIdx.x * blockDim.x + threadIdx.x;
  if (t < n) atomicAdd(&cnt[idx[t]], 1);
}

// ---- graph boundaries via binary search in SORTED batch: gb[g] = lower_bound(g) ----
__global__ void bounds_k(const int* __restrict__ batch, int* __restrict__ gb) {
  int g = threadIdx.x;
  if (g > NG) return;
  int lo = 0, hi = NND;
  while (lo < hi) {
    int mid = (lo + hi) >> 1;
    if (batch[mid] < g) lo = mid + 1; else hi = mid;
  }
  gb[g] = lo;
}

// ---- 3-stage grid scan of cnt[NND] -> offs (exclusive), cur, offs[NND]=total ----
__global__ __launch_bounds__(256) void bsum_k(const int* __restrict__ cnt,
                                              int* __restrict__ bsum) {
  __shared__ int s[256];
  int i = blockIdx.x * 256 + threadIdx.x;
  s[threadIdx.x] = (i < NND) ? cnt[i] : 0;
  __syncthreads();
  for (int off = 128; off > 0; off >>= 1) {
    if (threadIdx.x < off) s[threadIdx.x] += s[threadIdx.x + off];
    __syncthreads();
  }
  if (threadIdx.x == 0) bsum[blockIdx.x] = s[0];
}

__global__ __launch_bounds__(256) void bscan_k(const int* __restrict__ bsum,
                                               int* __restrict__ boff,
                                               int* __restrict__ offs) {
  __shared__ int s[256];
  int t = threadIdx.x;
  s[t] = (t < NBLK) ? bsum[t] : 0;
  __syncthreads();
  for (int off = 1; off < 256; off <<= 1) {   // inclusive Hillis-Steele
    int v = (t >= off) ? s[t - off] : 0;
    __syncthreads();
    s[t] += v;
    __syncthreads();
  }
  if (t < NBLK) boff[t] = (t == 0) ? 0 : s[t - 1];
  if (t == NBLK - 1) offs[NND] = s[t];        // grand total
}

__global__ __launch_bounds__(256) void escan_k(const int* __restrict__ cnt,
                                               const int* __restrict__ boff,
                                               int* __restrict__ offs,
                                               int* __restrict__ cur) {
  __shared__ int s[256];
  int i = blockIdx.x * 256 + threadIdx.x;
  int t = threadIdx.x;
  int v = (i < NND) ? cnt[i] : 0;
  s[t] = v;
  __syncthreads();
  for (int off = 1; off < 256; off <<= 1) {   // inclusive Hillis-Steele
    int u = (t >= off) ? s[t - off] : 0;
    __syncthreads();
    s[t] += u;
    __syncthreads();
  }
  if (i < NND) {
    int excl = s[t] - v + boff[blockIdx.x];   // inclusive - self = exclusive
    offs[i] = excl;
    cur[i]  = excl;
  }
}

// ---- CSR fill: csr[pos] = src for edges grouped by dst ----
__global__ void fill_k(const int* __restrict__ src, const int* __restrict__ dst,
                       int* __restrict__ cur, int* __restrict__ csr) {
  int e = blockIdx.x * blockDim.x + threadIdx.x;
  if (e >= NED) return;
  int d = dst[e];
  int pos = atomicAdd(&cur[d], 1);
  csr[pos] = src[e];
}

// ---- fp32 -> bf16 conversion (layer-0 input) ----
__global__ void cvt_k(const float* __restrict__ in, unsigned short* __restrict__ out) {
  int t = blockIdx.x * blockDim.x + threadIdx.x;   // one float4 chunk; NND*32 total
  if (t >= NND * 32) return;
  float4 v = reinterpret_cast<const float4*>(in)[t];
  u16x4 o;
  o.x = f2bf(v.x); o.y = f2bf(v.y); o.z = f2bf(v.z); o.w = f2bf(v.w);
  reinterpret_cast<u16x4*>(out)[t] = o;
}

// ---- all 8 weight transposes+converts in ONE launch: WT[n*128+k]=bf16(W[k*128+n]) ----
struct WPtrs { const float* w[8]; unsigned short* wt[8]; };
__global__ void wcvt8_k(WPtrs p) {
  int t = blockIdx.x * blockDim.x + threadIdx.x;   // 8 * 16384 total
  if (t >= 8 * CD * CD) return;
  int m = t >> 14, r = t & (CD * CD - 1);
  int n = r >> 7, k = r & 127;
  p.wt[m][r] = f2bf(p.w[m][k * CD + n]);
}

// ---- CSR gather-reduce v2: ab[n] = bf16( mean_{e in in(n)} xb[csr[e]] ) ----
// 16-lane team per dst node; lane owns 8 channels (one 16B u16x8 per edge).
// 8-edge-deep unroll -> 8 x 16B outstanding per lane (miss-latency hiding).
// Grid: NND*16 threads = 3125 blocks x 256, exact.
__global__ __launch_bounds__(256) void agg_k(const unsigned short* __restrict__ xb,
                                             const int* __restrict__ csr,
                                             const int* __restrict__ offs,
                                             unsigned short* __restrict__ ab) {
  const int team = (blockIdx.x * 256 + threadIdx.x) >> 4;   // == node id
  const int tl   = threadIdx.x & 15;
  const int e0 = offs[team], e1 = offs[team + 1];
  const unsigned short* base = xb + tl * 8;
  float a[8] = {};
  int e = e0;
  for (; e + 8 <= e1; e += 8) {
    int s[8];
#pragma unroll
    for (int j = 0; j < 8; ++j) s[j] = csr[e + j];
    u16x8 v[8];
#pragma unroll
    for (int j = 0; j < 8; ++j)
      v[j] = *reinterpret_cast<const u16x8*>(base + (size_t)s[j] * CD);
#pragma unroll
    for (int j = 0; j < 8; ++j)
#pragma unroll
      for (int c = 0; c < 8; ++c) a[c] += bf2f(v[j][c]);
  }
  for (; e + 4 <= e1; e += 4) {
    int s[4];
#pragma unroll
    for (int j = 0; j < 4; ++j) s[j] = csr[e + j];
    u16x8 v[4];
#pragma unroll
    for (int j = 0; j < 4; ++j)
      v[j] = *reinterpret_cast<const u16x8*>(base + (size_t)s[j] * CD);
#pragma unroll
    for (int j = 0; j < 4; ++j)
#pragma unroll
      for (int c = 0; c < 8; ++c) a[c] += bf2f(v[j][c]);
  }
  for (; e < e1; ++e) {
    u16x8 v = *reinterpret_cast<const u16x8*>(base + (size_t)csr[e] * CD);
#pragma unroll
    for (int c = 0; c < 8; ++c) a[c] += bf2f(v[c]);
  }
  const float invd = 1.0f / fmaxf((float)(e1 - e0), 1.0f);
  u16x8 o;
#pragma unroll
  for (int c = 0; c < 8; ++c) o[c] = f2bf(a[c] * invd);
  *reinterpret_cast<u16x8*>(ab + (size_t)team * CD + tl * 8) = o;
}

// ---- fused: h = relu(ab @ Wl + xb @ Wr + bias), bf16 out ----
// Wave w owns cols [w*32, w*32+32): its 16 B-frags (Wl+Wr, all K) live in
// registers, loaded ONCE per block. Both products accumulate into one acc.
// Block covers GROWS=64 rows (4 iters x 16). All layers write bf16.
// MFMA 16x16x32 bf16; A: m=lane&15,k=quad*8+j; B from WT[n][k]: n=lane&15;
// C/D: col=lane&15, row=quad*4+r (m89/m91-verified).
__global__ __launch_bounds__(256) void gemm2_k(
    const unsigned short* __restrict__ ab, const unsigned short* __restrict__ xb,
    const unsigned short* __restrict__ WlT, const unsigned short* __restrict__ WrT,
    const float* __restrict__ bias, unsigned short* __restrict__ hb) {
  const int wave = threadIdx.x >> 6;
  const int lane = threadIdx.x & 63;
  const int quad = lane >> 4;
  const int l16  = lane & 15;

  s8v bL[2][4], bR[2][4];
#pragma unroll
  for (int nt = 0; nt < 2; ++nt) {
    const int n = wave * 32 + nt * 16 + l16;
#pragma unroll
    for (int kk = 0; kk < 4; ++kk) {
      size_t woff = (size_t)n * CD + kk * 32 + quad * 8;
      bL[nt][kk] = *reinterpret_cast<const s8v*>(WlT + woff);
      bR[nt][kk] = *reinterpret_cast<const s8v*>(WrT + woff);
    }
  }
  const float bv0 = bias[wave * 32 + l16];
  const float bv1 = bias[wave * 32 + 16 + l16];

  const int rbase = blockIdx.x * GROWS;
#pragma unroll
  for (int rt = 0; rt < GROWS / 16; ++rt) {
    const int m0 = rbase + rt * 16;
    if (m0 >= NND) break;
    const int rowA  = m0 + l16;
    const int rowAc = rowA < NND ? rowA : NND - 1;
    s8v aA[4], aX[4];
#pragma unroll
    for (int kk = 0; kk < 4; ++kk) {
      size_t off = (size_t)rowAc * CD + kk * 32 + quad * 8;
      aA[kk] = *reinterpret_cast<const s8v*>(ab + off);
      aX[kk] = *reinterpret_cast<const s8v*>(xb + off);
    }
    f4v acc0 = {}, acc1 = {};
#pragma unroll
    for (int kk = 0; kk < 4; ++kk) {
      acc0 = __builtin_amdgcn_mfma_f32_16x16x32_bf16(aA[kk], bL[0][kk], acc0, 0, 0, 0);
      acc0 = __builtin_amdgcn_mfma_f32_16x16x32_bf16(aX[kk], bR[0][kk], acc0, 0, 0, 0);
      acc1 = __builtin_amdgcn_mfma_f32_16x16x32_bf16(aA[kk], bL[1][kk], acc1, 0, 0, 0);
      acc1 = __builtin_amdgcn_mfma_f32_16x16x32_bf16(aX[kk], bR[1][kk], acc1, 0, 0, 0);
    }
#pragma unroll
    for (int r = 0; r < 4; ++r) {
      const int row = m0 + quad * 4 + r;
      if (row < NND) {
        const int c0 = wave * 32 + l16;
        float v0 = fmaxf(acc0[r] + bv0, 0.0f);
        float v1 = fmaxf(acc1[r] + bv1, 0.0f);
        hb[(size_t)row * CD + c0]      = f2bf(v0);
        hb[(size_t)row * CD + c0 + 16] = f2bf(v1);
      }
    }
  }
}

// ---- mean-pool over bf16 features: 32-row chunks, one thread per channel,
// boundary-flush atomics; batch is SORTED. ----
__global__ __launch_bounds__(128) void pool3_k(const unsigned short* __restrict__ h,
                                               const int* __restrict__ batch,
                                               float* __restrict__ pooled) {
  const int c  = threadIdx.x;
  const int r0 = blockIdx.x * 32;
  const int rend = (r0 + 32 < NND) ? r0 + 32 : NND;
  const int g0 = batch[r0];
  const int g1 = batch[rend - 1];
  if (g0 == g1) {
    float acc = 0.f;
#pragma unroll
    for (int i = 0; i < 32; ++i) {
      int row = r0 + i;
      if (row < rend) acc += bf2f(h[(size_t)row * CD + c]);
    }
    atomicAdd(&pooled[g0 * CD + c], acc);
  } else {
    float acc = 0.f;
    int gcur = g0;
    for (int row = r0; row < rend; ++row) {
      int g = batch[row];
      if (g != gcur) {
        atomicAdd(&pooled[gcur * CD + c], acc);
        acc = 0.f; gcur = g;
      }
      acc += bf2f(h[(size_t)row * CD + c]);
    }
    atomicAdd(&pooled[gcur * CD + c], acc);
  }
}

// ---- classifier: out[g] = sigmoid(dot(pooled[g]/cnt, Wc) + bc) ----
__global__ void final_k(const float* __restrict__ pooled, const int* __restrict__ gb,
                        const float* __restrict__ Wc, const float* __restrict__ bc,
                        float* __restrict__ out) {
  int g = blockIdx.x;
  int lane = threadIdx.x;
  float part = pooled[g * CD + lane] * Wc[lane] +
               pooled[g * CD + 64 + lane] * Wc[64 + lane];
#pragma unroll
  for (int off = 32; off > 0; off >>= 1) part += __shfl_down(part, off, 64);
  if (lane == 0) {
    float cnt = (float)(gb[g + 1] - gb[g]);
    float z = part / fmaxf(cnt, 1.0f) + bc[0];
    out[g] = 1.0f / (1.0f + expf(-z));
  }
}

extern "C" void kernel_launch(void* const* d_in, const int* in_sizes, int n_in,
                              void* d_out, int out_size, void* d_ws, size_t ws_size,
                              hipStream_t stream) {
  const float* x   = (const float*)d_in[0];
  const int*   ei  = (const int*)d_in[1];
  const int*   src = ei;             // edge_index[0]
  const int*   dst = ei + NED;       // edge_index[1]
  // d_in[2] = edge_weight: unused by the reference
  const int*   batch = (const int*)d_in[3];
  const float* Wc = (const float*)d_in[16];
  const float* bc = (const float*)d_in[17];
  float* out = (float*)d_out;

  char* w = (char*)d_ws;
  auto alloc = [&](size_t bytes) {
    char* p = w; w += (bytes + 255) & ~(size_t)255; return p;
  };
  int* cnti = (int*)alloc(NND * 4);
  int* offs = (int*)alloc((NND + 1) * 4);
  int* cur  = (int*)alloc(NND * 4);
  int* csr  = (int*)alloc((size_t)NED * 4);
  int* gb   = (int*)alloc((NG + 1) * 4);
  int* bsum = (int*)alloc(256 * 4);
  int* boff = (int*)alloc(256 * 4);
  unsigned short* xb0 = (unsigned short*)alloc((size_t)NND * CD * 2);
  unsigned short* xb1 = (unsigned short*)alloc((size_t)NND * CD * 2);
  unsigned short* ab  = (unsigned short*)alloc((size_t)NND * CD * 2);
  WPtrs wp;
  for (int i = 0; i < 4; ++i) {
    wp.w[2 * i]     = (const float*)d_in[4 + 3 * i];      // Wl{i+1}
    wp.w[2 * i + 1] = (const float*)d_in[5 + 3 * i];      // Wr{i+1}
  }
  for (int i = 0; i < 8; ++i) wp.wt[i] = (unsigned short*)alloc(CD * CD * 2);
  const float* bs[4] = {(const float*)d_in[6],  (const float*)d_in[9],
                        (const float*)d_in[12], (const float*)d_in[15]};
  float* pooled = (float*)alloc(NG * CD * 4);

  hipMemsetAsync(cnti, 0, NND * 4, stream);
  hipMemsetAsync(pooled, 0, NG * CD * 4, stream);

  // CSR build (per call; inputs are restored before every timed launch)
  counti_k<<<(NED + 255) / 256, 256, 0, stream>>>(dst, cnti, NED);
  bsum_k<<<NBLK, 256, 0, stream>>>(cnti, bsum);
  bscan_k<<<1, 256, 0, stream>>>(bsum, boff, offs);
  escan_k<<<NBLK, 256, 0, stream>>>(cnti, boff, offs, cur);
  fill_k<<<(NED + 255) / 256, 256, 0, stream>>>(src, dst, cur, csr);
  bounds_k<<<1, 128, 0, stream>>>(batch, gb);

  cvt_k<<<(NND * 32 + 255) / 256, 256, 0, stream>>>(x, xb0);
  wcvt8_k<<<(8 * CD * CD + 255) / 256, 256, 0, stream>>>(wp);

  unsigned short* xcur = xb0;
  unsigned short* xnxt = xb1;
  const int ggrid = (NND + GROWS - 1) / GROWS;
  for (int l = 0; l < 4; ++l) {
    agg_k<<<NND * 16 / 256, 256, 0, stream>>>(xcur, csr, offs, ab);
    gemm2_k<<<ggrid, 256, 0, stream>>>(ab, xcur, wp.wt[2 * l], wp.wt[2 * l + 1],
                                       bs[l], xnxt);
    unsigned short* t = xcur; xcur = xnxt; xnxt = t;
  }

  pool3_k<<<(NND + 31) / 32, 128, 0, stream>>>(xcur, batch, pooled);
  final_k<<<NG, 64, 0, stream>>>(pooled, gb, Wc, bc, out);
}

// Round 9
// 367.027 us; speedup vs baseline: 1.1532x; 1.0718x over previous
//
#include <hip/hip_runtime.h>
#include <math.h>

// Problem constants (fixed by the reference)
#define NND 50000   // nodes
#define NED 600000  // edges
#define CD  128     // channels (in = hid = 128)
#define NG  64      // graphs
#define NBLK 196    // ceil(NND/256) scan blocks
#define GROWS 64    // rows per gemm block

typedef short s8v  __attribute__((ext_vector_type(8)));   // 8 bf16 (raw bits) = 4 VGPRs
typedef float f4v  __attribute__((ext_vector_type(4)));   // MFMA accumulator
typedef float f2v  __attribute__((ext_vector_type(2)));
typedef unsigned short u16x4 __attribute__((ext_vector_type(4)));
typedef unsigned short u16x8 __attribute__((ext_vector_type(8)));

static __device__ __forceinline__ unsigned short f2bf(float f) {
  union { float f; unsigned u; } v; v.f = f;
  unsigned r = v.u + 0x7fffu + ((v.u >> 16) & 1u);   // round-to-nearest-even
  return (unsigned short)(r >> 16);
}
static __device__ __forceinline__ float bf2f(unsigned short h) {
  union { unsigned u; float f; } v; v.u = ((unsigned)h) << 16; return v.f;
}
// 4 floats -> 4 packed OCP e4m3 bytes (HW RNE+sat)
static __device__ __forceinline__ unsigned f2fp8x4(float a, float b, float c, float d) {
  int r = __builtin_amdgcn_cvt_pk_fp8_f32(a, b, 0, false);
  r = __builtin_amdgcn_cvt_pk_fp8_f32(c, d, r, true);
  return (unsigned)r;
}

// ---- int degree count (CSR) ----
__global__ void counti_k(const int* __restrict__ idx, int* __restrict__ cnt, int n) {
  int t = blockIdx.x * blockDim.x + threadIdx.x;
  if (t < n) atomicAdd(&cnt[idx[t]], 1);
}

// ---- graph boundaries via binary search in SORTED batch: gb[g] = lower_bound(g) ----
__global__ void bounds_k(const int* __restrict__ batch, int* __restrict__ gb) {
  int g = threadIdx.x;
  if (g > NG) return;
  int lo = 0, hi = NND;
  while (lo < hi) {
    int mid = (lo + hi) >> 1;
    if (batch[mid] < g) lo = mid + 1; else hi = mid;
  }
  gb[g] = lo;
}

// ---- 3-stage grid scan of cnt[NND] -> offs (exclusive), cur, offs[NND]=total ----
__global__ __launch_bounds__(256) void bsum_k(const int* __restrict__ cnt,
                                              int* __restrict__ bsum) {
  __shared__ int s[256];
  int i = blockIdx.x * 256 + threadIdx.x;
  s[threadIdx.x] = (i < NND) ? cnt[i] : 0;
  __syncthreads();
  for (int off = 128; off > 0; off >>= 1) {
    if (threadIdx.x < off) s[threadIdx.x] += s[threadIdx.x + off];
    __syncthreads();
  }
  if (threadIdx.x == 0) bsum[blockIdx.x] = s[0];
}

__global__ __launch_bounds__(256) void bscan_k(const int* __restrict__ bsum,
                                               int* __restrict__ boff,
                                               int* __restrict__ offs) {
  __shared__ int s[256];
  int t = threadIdx.x;
  s[t] = (t < NBLK) ? bsum[t] : 0;
  __syncthreads();
  for (int off = 1; off < 256; off <<= 1) {   // inclusive Hillis-Steele
    int v = (t >= off) ? s[t - off] : 0;
    __syncthreads();
    s[t] += v;
    __syncthreads();
  }
  if (t < NBLK) boff[t] = (t == 0) ? 0 : s[t - 1];
  if (t == NBLK - 1) offs[NND] = s[t];        // grand total
}

__global__ __launch_bounds__(256) void escan_k(const int* __restrict__ cnt,
                                               const int* __restrict__ boff,
                                               int* __restrict__ offs,
                                               int* __restrict__ cur) {
  __shared__ int s[256];
  int i = blockIdx.x * 256 + threadIdx.x;
  int t = threadIdx.x;
  int v = (i < NND) ? cnt[i] : 0;
  s[t] = v;
  __syncthreads();
  for (int off = 1; off < 256; off <<= 1) {   // inclusive Hillis-Steele
    int u = (t >= off) ? s[t - off] : 0;
    __syncthreads();
    s[t] += u;
    __syncthreads();
  }
  if (i < NND) {
    int excl = s[t] - v + boff[blockIdx.x];   // inclusive - self = exclusive
    offs[i] = excl;
    cur[i]  = excl;
  }
}

// ---- CSR fill: csr[pos] = src for edges grouped by dst ----
__global__ void fill_k(const int* __restrict__ src, const int* __restrict__ dst,
                       int* __restrict__ cur, int* __restrict__ csr) {
  int e = blockIdx.x * blockDim.x + threadIdx.x;
  if (e >= NED) return;
  int d = dst[e];
  int pos = atomicAdd(&cur[d], 1);
  csr[pos] = src[e];
}

// ---- fp32 -> bf16 + fp8 conversion (layer-0 input) ----
__global__ void cvt_k(const float* __restrict__ in, unsigned short* __restrict__ out,
                      unsigned* __restrict__ o8) {
  int t = blockIdx.x * blockDim.x + threadIdx.x;   // one float4 chunk; NND*32 total
  if (t >= NND * 32) return;
  float4 v = reinterpret_cast<const float4*>(in)[t];
  u16x4 o;
  o.x = f2bf(v.x); o.y = f2bf(v.y); o.z = f2bf(v.z); o.w = f2bf(v.w);
  reinterpret_cast<u16x4*>(out)[t] = o;
  o8[t] = f2fp8x4(v.x, v.y, v.z, v.w);
}

// ---- all 8 weight transposes+converts in ONE launch: WT[n*128+k]=bf16(W[k*128+n]) ----
struct WPtrs { const float* w[8]; unsigned short* wt[8]; };
__global__ void wcvt8_k(WPtrs p) {
  int t = blockIdx.x * blockDim.x + threadIdx.x;   // 8 * 16384 total
  if (t >= 8 * CD * CD) return;
  int m = t >> 14, r = t & (CD * CD - 1);
  int n = r >> 7, k = r & 127;
  p.wt[m][r] = f2bf(p.w[m][k * CD + n]);
}

// ---- CSR gather-reduce v3 (fp8 table): ab[n] = bf16( mean xq[csr[e]] ) ----
// 16-lane team per dst node; lane owns 8 channels = ONE 8B uint2 per edge
// (full row = 128B = one cache line). 8-edge-deep unroll for MLP. Accumulate
// fp32 via HW packed fp8->f32 converts; mean emitted bf16 for the MFMA A path.
__global__ __launch_bounds__(256) void agg_k(const unsigned* __restrict__ xq,
                                             const int* __restrict__ csr,
                                             const int* __restrict__ offs,
                                             unsigned short* __restrict__ ab) {
  const int team = (blockIdx.x * 256 + threadIdx.x) >> 4;   // == node id
  const int tl   = threadIdx.x & 15;
  const int e0 = offs[team], e1 = offs[team + 1];
  const unsigned* base = xq + tl * 2;            // 2 u32 = 8 fp8 channels
  f2v a01 = {0.f, 0.f}, a23 = {0.f, 0.f}, a45 = {0.f, 0.f}, a67 = {0.f, 0.f};
  int e = e0;
  for (; e + 8 <= e1; e += 8) {
    int s[8];
#pragma unroll
    for (int j = 0; j < 8; ++j) s[j] = csr[e + j];
    uint2 v[8];
#pragma unroll
    for (int j = 0; j < 8; ++j)
      v[j] = *reinterpret_cast<const uint2*>(base + (size_t)s[j] * 32);
#pragma unroll
    for (int j = 0; j < 8; ++j) {
      a01 += __builtin_amdgcn_cvt_pk_f32_fp8(v[j].x, false);
      a23 += __builtin_amdgcn_cvt_pk_f32_fp8(v[j].x, true);
      a45 += __builtin_amdgcn_cvt_pk_f32_fp8(v[j].y, false);
      a67 += __builtin_amdgcn_cvt_pk_f32_fp8(v[j].y, true);
    }
  }
  for (; e + 4 <= e1; e += 4) {
    int s[4];
#pragma unroll
    for (int j = 0; j < 4; ++j) s[j] = csr[e + j];
    uint2 v[4];
#pragma unroll
    for (int j = 0; j < 4; ++j)
      v[j] = *reinterpret_cast<const uint2*>(base + (size_t)s[j] * 32);
#pragma unroll
    for (int j = 0; j < 4; ++j) {
      a01 += __builtin_amdgcn_cvt_pk_f32_fp8(v[j].x, false);
      a23 += __builtin_amdgcn_cvt_pk_f32_fp8(v[j].x, true);
      a45 += __builtin_amdgcn_cvt_pk_f32_fp8(v[j].y, false);
      a67 += __builtin_amdgcn_cvt_pk_f32_fp8(v[j].y, true);
    }
  }
  for (; e < e1; ++e) {
    uint2 v = *reinterpret_cast<const uint2*>(base + (size_t)csr[e] * 32);
    a01 += __builtin_amdgcn_cvt_pk_f32_fp8(v.x, false);
    a23 += __builtin_amdgcn_cvt_pk_f32_fp8(v.x, true);
    a45 += __builtin_amdgcn_cvt_pk_f32_fp8(v.y, false);
    a67 += __builtin_amdgcn_cvt_pk_f32_fp8(v.y, true);
  }
  const float invd = 1.0f / fmaxf((float)(e1 - e0), 1.0f);
  u16x8 o;
  o[0] = f2bf(a01.x * invd); o[1] = f2bf(a01.y * invd);
  o[2] = f2bf(a23.x * invd); o[3] = f2bf(a23.y * invd);
  o[4] = f2bf(a45.x * invd); o[5] = f2bf(a45.y * invd);
  o[6] = f2bf(a67.x * invd); o[7] = f2bf(a67.y * invd);
  *reinterpret_cast<u16x8*>(ab + (size_t)team * CD + tl * 8) = o;
}

// ---- fused: h = relu(ab @ Wl + xb @ Wr + bias); bf16 out + optional fp8 copy ----
// Wave w owns cols [w*32, w*32+32): 16 B-frags (Wl+Wr) register-resident,
// loaded ONCE per block; both products in one accumulator; 64 rows/block.
// MFMA 16x16x32 bf16; A: m=lane&15,k=quad*8+j; B from WT[n][k]: n=lane&15;
// C/D: col=lane&15, row=quad*4+r (m89/m91-verified).
__global__ __launch_bounds__(256) void gemm2_k(
    const unsigned short* __restrict__ ab, const unsigned short* __restrict__ xb,
    const unsigned short* __restrict__ WlT, const unsigned short* __restrict__ WrT,
    const float* __restrict__ bias, unsigned short* __restrict__ hb,
    unsigned char* __restrict__ h8) {
  const int wave = threadIdx.x >> 6;
  const int lane = threadIdx.x & 63;
  const int quad = lane >> 4;
  const int l16  = lane & 15;

  s8v bL[2][4], bR[2][4];
#pragma unroll
  for (int nt = 0; nt < 2; ++nt) {
    const int n = wave * 32 + nt * 16 + l16;
#pragma unroll
    for (int kk = 0; kk < 4; ++kk) {
      size_t woff = (size_t)n * CD + kk * 32 + quad * 8;
      bL[nt][kk] = *reinterpret_cast<const s8v*>(WlT + woff);
      bR[nt][kk] = *reinterpret_cast<const s8v*>(WrT + woff);
    }
  }
  const float bv0 = bias[wave * 32 + l16];
  const float bv1 = bias[wave * 32 + 16 + l16];

  const int rbase = blockIdx.x * GROWS;
#pragma unroll
  for (int rt = 0; rt < GROWS / 16; ++rt) {
    const int m0 = rbase + rt * 16;
    if (m0 >= NND) break;
    const int rowA  = m0 + l16;
    const int rowAc = rowA < NND ? rowA : NND - 1;
    s8v aA[4], aX[4];
#pragma unroll
    for (int kk = 0; kk < 4; ++kk) {
      size_t off = (size_t)rowAc * CD + kk * 32 + quad * 8;
      aA[kk] = *reinterpret_cast<const s8v*>(ab + off);
      aX[kk] = *reinterpret_cast<const s8v*>(xb + off);
    }
    f4v acc0 = {}, acc1 = {};
#pragma unroll
    for (int kk = 0; kk < 4; ++kk) {
      acc0 = __builtin_amdgcn_mfma_f32_16x16x32_bf16(aA[kk], bL[0][kk], acc0, 0, 0, 0);
      acc0 = __builtin_amdgcn_mfma_f32_16x16x32_bf16(aX[kk], bR[0][kk], acc0, 0, 0, 0);
      acc1 = __builtin_amdgcn_mfma_f32_16x16x32_bf16(aA[kk], bL[1][kk], acc1, 0, 0, 0);
      acc1 = __builtin_amdgcn_mfma_f32_16x16x32_bf16(aX[kk], bR[1][kk], acc1, 0, 0, 0);
    }
#pragma unroll
    for (int r = 0; r < 4; ++r) {
      const int row = m0 + quad * 4 + r;
      if (row < NND) {
        const int c0 = wave * 32 + l16;
        float v0 = fmaxf(acc0[r] + bv0, 0.0f);
        float v1 = fmaxf(acc1[r] + bv1, 0.0f);
        hb[(size_t)row * CD + c0]      = f2bf(v0);
        hb[(size_t)row * CD + c0 + 16] = f2bf(v1);
        if (h8) {
          int p0 = __builtin_amdgcn_cvt_pk_fp8_f32(v0, v0, 0, false);
          int p1 = __builtin_amdgcn_cvt_pk_fp8_f32(v1, v1, 0, false);
          h8[(size_t)row * CD + c0]      = (unsigned char)p0;
          h8[(size_t)row * CD + c0 + 16] = (unsigned char)p1;
        }
      }
    }
  }
}

// ---- mean-pool over bf16 features: 32-row chunks, one thread per channel,
// boundary-flush atomics; batch is SORTED. ----
__global__ __launch_bounds__(128) void pool3_k(const unsigned short* __restrict__ h,
                                               const int* __restrict__ batch,
                                               float* __restrict__ pooled) {
  const int c  = threadIdx.x;
  const int r0 = blockIdx.x * 32;
  const int rend = (r0 + 32 < NND) ? r0 + 32 : NND;
  const int g0 = batch[r0];
  const int g1 = batch[rend - 1];
  if (g0 == g1) {
    float acc = 0.f;
#pragma unroll
    for (int i = 0; i < 32; ++i) {
      int row = r0 + i;
      if (row < rend) acc += bf2f(h[(size_t)row * CD + c]);
    }
    atomicAdd(&pooled[g0 * CD + c], acc);
  } else {
    float acc = 0.f;
    int gcur = g0;
    for (int row = r0; row < rend; ++row) {
      int g = batch[row];
      if (g != gcur) {
        atomicAdd(&pooled[gcur * CD + c], acc);
        acc = 0.f; gcur = g;
      }
      acc += bf2f(h[(size_t)row * CD + c]);
    }
    atomicAdd(&pooled[gcur * CD + c], acc);
  }
}

// ---- classifier: out[g] = sigmoid(dot(pooled[g]/cnt, Wc) + bc) ----
__global__ void final_k(const float* __restrict__ pooled, const int* __restrict__ gb,
                        const float* __restrict__ Wc, const float* __restrict__ bc,
                        float* __restrict__ out) {
  int g = blockIdx.x;
  int lane = threadIdx.x;
  float part = pooled[g * CD + lane] * Wc[lane] +
               pooled[g * CD + 64 + lane] * Wc[64 + lane];
#pragma unroll
  for (int off = 32; off > 0; off >>= 1) part += __shfl_down(part, off, 64);
  if (lane == 0) {
    float cnt = (float)(gb[g + 1] - gb[g]);
    float z = part / fmaxf(cnt, 1.0f) + bc[0];
    out[g] = 1.0f / (1.0f + expf(-z));
  }
}

extern "C" void kernel_launch(void* const* d_in, const int* in_sizes, int n_in,
                              void* d_out, int out_size, void* d_ws, size_t ws_size,
                              hipStream_t stream) {
  const float* x   = (const float*)d_in[0];
  const int*   ei  = (const int*)d_in[1];
  const int*   src = ei;             // edge_index[0]
  const int*   dst = ei + NED;       // edge_index[1]
  // d_in[2] = edge_weight: unused by the reference
  const int*   batch = (const int*)d_in[3];
  const float* Wc = (const float*)d_in[16];
  const float* bc = (const float*)d_in[17];
  float* out = (float*)d_out;

  char* w = (char*)d_ws;
  auto alloc = [&](size_t bytes) {
    char* p = w; w += (bytes + 255) & ~(size_t)255; return p;
  };
  int* cnti = (int*)alloc(NND * 4);
  int* offs = (int*)alloc((NND + 1) * 4);
  int* cur  = (int*)alloc(NND * 4);
  int* csr  = (int*)alloc((size_t)NED * 4);
  int* gb   = (int*)alloc((NG + 1) * 4);
  int* bsum = (int*)alloc(256 * 4);
  int* boff = (int*)alloc(256 * 4);
  unsigned short* xb0 = (unsigned short*)alloc((size_t)NND * CD * 2);
  unsigned short* xb1 = (unsigned short*)alloc((size_t)NND * CD * 2);
  unsigned short* ab  = (unsigned short*)alloc((size_t)NND * CD * 2);
  unsigned char* x8a = (unsigned char*)alloc((size_t)NND * CD);
  unsigned char* x8b = (unsigned char*)alloc((size_t)NND * CD);
  WPtrs wp;
  for (int i = 0; i < 4; ++i) {
    wp.w[2 * i]     = (const float*)d_in[4 + 3 * i];      // Wl{i+1}
    wp.w[2 * i + 1] = (const float*)d_in[5 + 3 * i];      // Wr{i+1}
  }
  for (int i = 0; i < 8; ++i) wp.wt[i] = (unsigned short*)alloc(CD * CD * 2);
  const float* bs[4] = {(const float*)d_in[6],  (const float*)d_in[9],
                        (const float*)d_in[12], (const float*)d_in[15]};
  float* pooled = (float*)alloc(NG * CD * 4);

  hipMemsetAsync(cnti, 0, NND * 4, stream);
  hipMemsetAsync(pooled, 0, NG * CD * 4, stream);

  // CSR build (per call; inputs are restored before every timed launch)
  counti_k<<<(NED + 255) / 256, 256, 0, stream>>>(dst, cnti, NED);
  bsum_k<<<NBLK, 256, 0, stream>>>(cnti, bsum);
  bscan_k<<<1, 256, 0, stream>>>(bsum, boff, offs);
  escan_k<<<NBLK, 256, 0, stream>>>(cnti, boff, offs, cur);
  fill_k<<<(NED + 255) / 256, 256, 0, stream>>>(src, dst, cur, csr);
  bounds_k<<<1, 128, 0, stream>>>(batch, gb);

  cvt_k<<<(NND * 32 + 255) / 256, 256, 0, stream>>>(x, xb0, (unsigned*)x8a);
  wcvt8_k<<<(8 * CD * CD + 255) / 256, 256, 0, stream>>>(wp);

  unsigned short* xcur = xb0;
  unsigned short* xnxt = xb1;
  unsigned char* qcur = x8a;
  unsigned char* qnxt = x8b;
  const int ggrid = (NND + GROWS - 1) / GROWS;
  for (int l = 0; l < 4; ++l) {
    agg_k<<<NND * 16 / 256, 256, 0, stream>>>((const unsigned*)qcur, csr, offs, ab);
    gemm2_k<<<ggrid, 256, 0, stream>>>(ab, xcur, wp.wt[2 * l], wp.wt[2 * l + 1],
                                       bs[l], xnxt, (l < 3) ? qnxt : nullptr);
    unsigned short* t = xcur; xcur = xnxt; xnxt = t;
    unsigned char* q = qcur; qcur = qnxt; qnxt = q;
  }

  pool3_k<<<(NND + 31) / 32, 128, 0, stream>>>(xcur, batch, pooled);
  final_k<<<NG, 64, 0, stream>>>(pooled, gb, Wc, bc, out);
}

// Round 10
// 360.183 us; speedup vs baseline: 1.1751x; 1.0190x over previous
//
#include <hip/hip_runtime.h>
#include <math.h>

// Problem constants (fixed by the reference)
#define NND 50000   // nodes
#define LNP 50048   // padded rows: 782 * 64, guard-free gemm
#define NED 600000  // edges
#define CD  128     // channels (in = hid = 128)
#define NG  64      // graphs
#define NBLK 196    // ceil(NND/256) scan blocks
#define GROWS 64    // rows per gemm block

typedef short s8v  __attribute__((ext_vector_type(8)));   // 8 bf16 (raw bits) = 4 VGPRs
typedef float f4v  __attribute__((ext_vector_type(4)));   // MFMA accumulator
typedef float f2v  __attribute__((ext_vector_type(2)));
typedef unsigned short u16x4 __attribute__((ext_vector_type(4)));
typedef unsigned short u16x8 __attribute__((ext_vector_type(8)));

static __device__ __forceinline__ unsigned short f2bf(float f) {
  union { float f; unsigned u; } v; v.f = f;
  unsigned r = v.u + 0x7fffu + ((v.u >> 16) & 1u);   // round-to-nearest-even
  return (unsigned short)(r >> 16);
}
static __device__ __forceinline__ float bf2f(unsigned short h) {
  union { unsigned u; float f; } v; v.u = ((unsigned)h) << 16; return v.f;
}
// 4 floats -> 4 packed OCP e4m3 bytes (HW RNE+sat)
static __device__ __forceinline__ unsigned f2fp8x4(float a, float b, float c, float d) {
  int r = __builtin_amdgcn_cvt_pk_fp8_f32(a, b, 0, false);
  r = __builtin_amdgcn_cvt_pk_fp8_f32(c, d, r, true);
  return (unsigned)r;
}

// ---- int degree count (CSR) ----
__global__ void counti_k(const int* __restrict__ idx, int* __restrict__ cnt, int n) {
  int t = blockIdx.x * blockDim.x + threadIdx.x;
  if (t < n) atomicAdd(&cnt[idx[t]], 1);
}

// ---- 3-stage grid scan of cnt[NND] -> offs (exclusive), cur, offs[NND]=total ----
__global__ __launch_bounds__(256) void bsum_k(const int* __restrict__ cnt,
                                              int* __restrict__ bsum) {
  __shared__ int s[256];
  int i = blockIdx.x * 256 + threadIdx.x;
  s[threadIdx.x] = (i < NND) ? cnt[i] : 0;
  __syncthreads();
  for (int off = 128; off > 0; off >>= 1) {
    if (threadIdx.x < off) s[threadIdx.x] += s[threadIdx.x + off];
    __syncthreads();
  }
  if (threadIdx.x == 0) bsum[blockIdx.x] = s[0];
}

// also folds in graph-boundary binary search (batch is SORTED): gb[g]=lower_bound(g)
__global__ __launch_bounds__(256) void bscan_k(const int* __restrict__ bsum,
                                               int* __restrict__ boff,
                                               int* __restrict__ offs,
                                               const int* __restrict__ batch,
                                               int* __restrict__ gb) {
  __shared__ int s[256];
  int t = threadIdx.x;
  if (t <= NG) {
    int lo = 0, hi = NND;
    while (lo < hi) {
      int mid = (lo + hi) >> 1;
      if (batch[mid] < t) lo = mid + 1; else hi = mid;
    }
    gb[t] = lo;
  }
  s[t] = (t < NBLK) ? bsum[t] : 0;
  __syncthreads();
  for (int off = 1; off < 256; off <<= 1) {   // inclusive Hillis-Steele
    int v = (t >= off) ? s[t - off] : 0;
    __syncthreads();
    s[t] += v;
    __syncthreads();
  }
  if (t < NBLK) boff[t] = (t == 0) ? 0 : s[t - 1];
  if (t == NBLK - 1) offs[NND] = s[t];        // grand total
}

__global__ __launch_bounds__(256) void escan_k(const int* __restrict__ cnt,
                                               const int* __restrict__ boff,
                                               int* __restrict__ offs,
                                               int* __restrict__ cur) {
  __shared__ int s[256];
  int i = blockIdx.x * 256 + threadIdx.x;
  int t = threadIdx.x;
  int v = (i < NND) ? cnt[i] : 0;
  s[t] = v;
  __syncthreads();
  for (int off = 1; off < 256; off <<= 1) {   // inclusive Hillis-Steele
    int u = (t >= off) ? s[t - off] : 0;
    __syncthreads();
    s[t] += u;
    __syncthreads();
  }
  if (i < NND) {
    int excl = s[t] - v + boff[blockIdx.x];   // inclusive - self = exclusive
    offs[i] = excl;
    cur[i]  = excl;
  }
}

// ---- CSR fill: csr[pos] = src for edges grouped by dst ----
__global__ void fill_k(const int* __restrict__ src, const int* __restrict__ dst,
                       int* __restrict__ cur, int* __restrict__ csr) {
  int e = blockIdx.x * blockDim.x + threadIdx.x;
  if (e >= NED) return;
  int d = dst[e];
  int pos = atomicAdd(&cur[d], 1);
  csr[pos] = src[e];
}

// ---- merged preamble: x -> bf16 + fp8 (range 0) and 8 weight transposes (range 1) ----
struct WPtrs { const float* w[8]; unsigned short* wt[8]; };
__global__ void prep_k(const float* __restrict__ x, unsigned short* __restrict__ xb,
                       unsigned* __restrict__ x8, WPtrs p) {
  int t = blockIdx.x * blockDim.x + threadIdx.x;
  if (t < NND * 32) {                 // one float4 chunk per thread
    float4 v = reinterpret_cast<const float4*>(x)[t];
    u16x4 o;
    o.x = f2bf(v.x); o.y = f2bf(v.y); o.z = f2bf(v.z); o.w = f2bf(v.w);
    reinterpret_cast<u16x4*>(xb)[t] = o;
    x8[t] = f2fp8x4(v.x, v.y, v.z, v.w);
  } else {
    int u = t - NND * 32;             // 8*16384 weight elements
    if (u < 8 * CD * CD) {
      int m = u >> 14, r = u & (CD * CD - 1);
      int n = r >> 7, k = r & 127;
      p.wt[m][r] = f2bf(p.w[m][k * CD + n]);
    }
  }
}

// ---- CSR gather-reduce v3 (fp8 table): ab[n] = bf16( mean xq[csr[e]] ) ----
// 16-lane team per dst node; lane owns 8 channels = ONE 8B uint2 per edge
// (full row = 128B = one cache line). 8-edge-deep unroll for MLP. Accumulate
// fp32 via HW packed fp8->f32 converts; mean emitted bf16 for the MFMA A path.
__global__ __launch_bounds__(256) void agg_k(const unsigned* __restrict__ xq,
                                             const int* __restrict__ csr,
                                             const int* __restrict__ offs,
                                             unsigned short* __restrict__ ab) {
  const int team = (blockIdx.x * 256 + threadIdx.x) >> 4;   // == node id
  const int tl   = threadIdx.x & 15;
  const int e0 = offs[team], e1 = offs[team + 1];
  const unsigned* base = xq + tl * 2;            // 2 u32 = 8 fp8 channels
  f2v a01 = {0.f, 0.f}, a23 = {0.f, 0.f}, a45 = {0.f, 0.f}, a67 = {0.f, 0.f};
  int e = e0;
  for (; e + 8 <= e1; e += 8) {
    int s[8];
#pragma unroll
    for (int j = 0; j < 8; ++j) s[j] = csr[e + j];
    uint2 v[8];
#pragma unroll
    for (int j = 0; j < 8; ++j)
      v[j] = *reinterpret_cast<const uint2*>(base + (size_t)s[j] * 32);
#pragma unroll
    for (int j = 0; j < 8; ++j) {
      a01 += __builtin_amdgcn_cvt_pk_f32_fp8(v[j].x, false);
      a23 += __builtin_amdgcn_cvt_pk_f32_fp8(v[j].x, true);
      a45 += __builtin_amdgcn_cvt_pk_f32_fp8(v[j].y, false);
      a67 += __builtin_amdgcn_cvt_pk_f32_fp8(v[j].y, true);
    }
  }
  for (; e + 4 <= e1; e += 4) {
    int s[4];
#pragma unroll
    for (int j = 0; j < 4; ++j) s[j] = csr[e + j];
    uint2 v[4];
#pragma unroll
    for (int j = 0; j < 4; ++j)
      v[j] = *reinterpret_cast<const uint2*>(base + (size_t)s[j] * 32);
#pragma unroll
    for (int j = 0; j < 4; ++j) {
      a01 += __builtin_amdgcn_cvt_pk_f32_fp8(v[j].x, false);
      a23 += __builtin_amdgcn_cvt_pk_f32_fp8(v[j].x, true);
      a45 += __builtin_amdgcn_cvt_pk_f32_fp8(v[j].y, false);
      a67 += __builtin_amdgcn_cvt_pk_f32_fp8(v[j].y, true);
    }
  }
  for (; e < e1; ++e) {
    uint2 v = *reinterpret_cast<const uint2*>(base + (size_t)csr[e] * 32);
    a01 += __builtin_amdgcn_cvt_pk_f32_fp8(v.x, false);
    a23 += __builtin_amdgcn_cvt_pk_f32_fp8(v.x, true);
    a45 += __builtin_amdgcn_cvt_pk_f32_fp8(v.y, false);
    a67 += __builtin_amdgcn_cvt_pk_f32_fp8(v.y, true);
  }
  const float invd = 1.0f / fmaxf((float)(e1 - e0), 1.0f);
  u16x8 o;
  o[0] = f2bf(a01.x * invd); o[1] = f2bf(a01.y * invd);
  o[2] = f2bf(a23.x * invd); o[3] = f2bf(a23.y * invd);
  o[4] = f2bf(a45.x * invd); o[5] = f2bf(a45.y * invd);
  o[6] = f2bf(a67.x * invd); o[7] = f2bf(a67.y * invd);
  *reinterpret_cast<u16x8*>(ab + (size_t)team * CD + tl * 8) = o;
}

// ---- fused: h = relu(ab @ Wl + xb @ Wr + bias); bf16 out + optional fp8 copy ----
// GUARD-FREE: buffers padded to LNP rows, grid = LNP/GROWS. Wave w owns cols
// [w*32,w*32+32): 16 B-frags register-resident. Depth-2 software pipeline:
// prefetch iter rt+1's A-frags during iter rt's MFMA.
// MFMA 16x16x32 bf16; A: m=lane&15,k=quad*8+j; B from WT[n][k]: n=lane&15;
// C/D: col=lane&15, row=quad*4+r (m89/m91-verified).
__global__ __launch_bounds__(256) void gemm2_k(
    const unsigned short* __restrict__ ab, const unsigned short* __restrict__ xb,
    const unsigned short* __restrict__ WlT, const unsigned short* __restrict__ WrT,
    const float* __restrict__ bias, unsigned short* __restrict__ hb,
    unsigned char* __restrict__ h8) {
  const int wave = threadIdx.x >> 6;
  const int lane = threadIdx.x & 63;
  const int quad = lane >> 4;
  const int l16  = lane & 15;

  s8v bL[2][4], bR[2][4];
#pragma unroll
  for (int nt = 0; nt < 2; ++nt) {
    const int n = wave * 32 + nt * 16 + l16;
#pragma unroll
    for (int kk = 0; kk < 4; ++kk) {
      size_t woff = (size_t)n * CD + kk * 32 + quad * 8;
      bL[nt][kk] = *reinterpret_cast<const s8v*>(WlT + woff);
      bR[nt][kk] = *reinterpret_cast<const s8v*>(WrT + woff);
    }
  }
  const float bv0 = bias[wave * 32 + l16];
  const float bv1 = bias[wave * 32 + 16 + l16];

  const size_t rbase = (size_t)blockIdx.x * GROWS;
  const unsigned short* aptr = ab + (rbase + l16) * CD + quad * 8;
  const unsigned short* xptr = xb + (rbase + l16) * CD + quad * 8;

  s8v aA[2][4], aX[2][4];
#pragma unroll
  for (int kk = 0; kk < 4; ++kk) {
    aA[0][kk] = *reinterpret_cast<const s8v*>(aptr + kk * 32);
    aX[0][kk] = *reinterpret_cast<const s8v*>(xptr + kk * 32);
  }

#pragma unroll
  for (int rt = 0; rt < GROWS / 16; ++rt) {
    const int cb = rt & 1, nb = cb ^ 1;
    if (rt < GROWS / 16 - 1) {
      const unsigned short* ap = aptr + (size_t)(rt + 1) * 16 * CD;
      const unsigned short* xp = xptr + (size_t)(rt + 1) * 16 * CD;
#pragma unroll
      for (int kk = 0; kk < 4; ++kk) {
        aA[nb][kk] = *reinterpret_cast<const s8v*>(ap + kk * 32);
        aX[nb][kk] = *reinterpret_cast<const s8v*>(xp + kk * 32);
      }
    }
    f4v acc0 = {}, acc1 = {};
#pragma unroll
    for (int kk = 0; kk < 4; ++kk) {
      acc0 = __builtin_amdgcn_mfma_f32_16x16x32_bf16(aA[cb][kk], bL[0][kk], acc0, 0, 0, 0);
      acc0 = __builtin_amdgcn_mfma_f32_16x16x32_bf16(aX[cb][kk], bR[0][kk], acc0, 0, 0, 0);
      acc1 = __builtin_amdgcn_mfma_f32_16x16x32_bf16(aA[cb][kk], bL[1][kk], acc1, 0, 0, 0);
      acc1 = __builtin_amdgcn_mfma_f32_16x16x32_bf16(aX[cb][kk], bR[1][kk], acc1, 0, 0, 0);
    }
    const size_t row0 = rbase + rt * 16 + quad * 4;
    const int c0 = wave * 32 + l16;
#pragma unroll
    for (int r = 0; r < 4; ++r) {
      const size_t row = row0 + r;
      float v0 = fmaxf(acc0[r] + bv0, 0.0f);
      float v1 = fmaxf(acc1[r] + bv1, 0.0f);
      hb[row * CD + c0]      = f2bf(v0);
      hb[row * CD + c0 + 16] = f2bf(v1);
      if (h8) {
        int p0 = __builtin_amdgcn_cvt_pk_fp8_f32(v0, v0, 0, false);
        int p1 = __builtin_amdgcn_cvt_pk_fp8_f32(v1, v1, 0, false);
        h8[row * CD + c0]      = (unsigned char)p0;
        h8[row * CD + c0 + 16] = (unsigned char)p1;
      }
    }
  }
}

// ---- mean-pool over bf16 features: 32-row chunks, one thread per channel,
// boundary-flush atomics; batch is SORTED. ----
__global__ __launch_bounds__(128) void pool3_k(const unsigned short* __restrict__ h,
                                               const int* __restrict__ batch,
                                               float* __restrict__ pooled) {
  const int c  = threadIdx.x;
  const int r0 = blockIdx.x * 32;
  const int rend = (r0 + 32 < NND) ? r0 + 32 : NND;
  const int g0 = batch[r0];
  const int g1 = batch[rend - 1];
  if (g0 == g1) {
    float acc = 0.f;
#pragma unroll
    for (int i = 0; i < 32; ++i) {
      int row = r0 + i;
      if (row < rend) acc += bf2f(h[(size_t)row * CD + c]);
    }
    atomicAdd(&pooled[g0 * CD + c], acc);
  } else {
    float acc = 0.f;
    int gcur = g0;
    for (int row = r0; row < rend; ++row) {
      int g = batch[row];
      if (g != gcur) {
        atomicAdd(&pooled[gcur * CD + c], acc);
        acc = 0.f; gcur = g;
      }
      acc += bf2f(h[(size_t)row * CD + c]);
    }
    atomicAdd(&pooled[gcur * CD + c], acc);
  }
}

// ---- classifier: out[g] = sigmoid(dot(pooled[g]/cnt, Wc) + bc) ----
__global__ void final_k(const float* __restrict__ pooled, const int* __restrict__ gb,
                        const float* __restrict__ Wc, const float* __restrict__ bc,
                        float* __restrict__ out) {
  int g = blockIdx.x;
  int lane = threadIdx.x;
  float part = pooled[g * CD + lane] * Wc[lane] +
               pooled[g * CD + 64 + lane] * Wc[64 + lane];
#pragma unroll
  for (int off = 32; off > 0; off >>= 1) part += __shfl_down(part, off, 64);
  if (lane == 0) {
    float cnt = (float)(gb[g + 1] - gb[g]);
    float z = part / fmaxf(cnt, 1.0f) + bc[0];
    out[g] = 1.0f / (1.0f + expf(-z));
  }
}

extern "C" void kernel_launch(void* const* d_in, const int* in_sizes, int n_in,
                              void* d_out, int out_size, void* d_ws, size_t ws_size,
                              hipStream_t stream) {
  const float* x   = (const float*)d_in[0];
  const int*   ei  = (const int*)d_in[1];
  const int*   src = ei;             // edge_index[0]
  const int*   dst = ei + NED;       // edge_index[1]
  // d_in[2] = edge_weight: unused by the reference
  const int*   batch = (const int*)d_in[3];
  const float* Wc = (const float*)d_in[16];
  const float* bc = (const float*)d_in[17];
  float* out = (float*)d_out;

  char* w = (char*)d_ws;
  auto alloc = [&](size_t bytes) {
    char* p = w; w += (bytes + 255) & ~(size_t)255; return p;
  };
  // cnti + pooled first and contiguous: one memset covers both
  int* cnti = (int*)alloc(NND * 4);
  float* pooled = (float*)alloc(NG * CD * 4);
  size_t zspan = (size_t)(w - (char*)cnti);
  int* offs = (int*)alloc((NND + 1) * 4);
  int* cur  = (int*)alloc(NND * 4);
  int* csr  = (int*)alloc((size_t)NED * 4);
  int* gb   = (int*)alloc((NG + 1) * 4);
  int* bsum = (int*)alloc(256 * 4);
  int* boff = (int*)alloc(256 * 4);
  unsigned short* xb0 = (unsigned short*)alloc((size_t)LNP * CD * 2);
  unsigned short* xb1 = (unsigned short*)alloc((size_t)LNP * CD * 2);
  unsigned short* ab  = (unsigned short*)alloc((size_t)LNP * CD * 2);
  unsigned char* x8a = (unsigned char*)alloc((size_t)LNP * CD);
  unsigned char* x8b = (unsigned char*)alloc((size_t)LNP * CD);
  WPtrs wp;
  for (int i = 0; i < 4; ++i) {
    wp.w[2 * i]     = (const float*)d_in[4 + 3 * i];      // Wl{i+1}
    wp.w[2 * i + 1] = (const float*)d_in[5 + 3 * i];      // Wr{i+1}
  }
  for (int i = 0; i < 8; ++i) wp.wt[i] = (unsigned short*)alloc(CD * CD * 2);
  const float* bs[4] = {(const float*)d_in[6],  (const float*)d_in[9],
                        (const float*)d_in[12], (const float*)d_in[15]};

  hipMemsetAsync(cnti, 0, zspan, stream);

  // CSR build (per call; inputs are restored before every timed launch)
  counti_k<<<(NED + 255) / 256, 256, 0, stream>>>(dst, cnti, NED);
  bsum_k<<<NBLK, 256, 0, stream>>>(cnti, bsum);
  bscan_k<<<1, 256, 0, stream>>>(bsum, boff, offs, batch, gb);
  escan_k<<<NBLK, 256, 0, stream>>>(cnti, boff, offs, cur);
  fill_k<<<(NED + 255) / 256, 256, 0, stream>>>(src, dst, cur, csr);

  prep_k<<<(NND * 32 + 8 * CD * CD + 255) / 256, 256, 0, stream>>>(
      x, xb0, (unsigned*)x8a, wp);

  unsigned short* xcur = xb0;
  unsigned short* xnxt = xb1;
  unsigned char* qcur = x8a;
  unsigned char* qnxt = x8b;
  const int ggrid = LNP / GROWS;   // 782, guard-free
  for (int l = 0; l < 4; ++l) {
    agg_k<<<NND * 16 / 256, 256, 0, stream>>>((const unsigned*)qcur, csr, offs, ab);
    gemm2_k<<<ggrid, 256, 0, stream>>>(ab, xcur, wp.wt[2 * l], wp.wt[2 * l + 1],
                                       bs[l], xnxt, (l < 3) ? qnxt : nullptr);
    unsigned short* t = xcur; xcur = xnxt; xnxt = t;
    unsigned char* q = qcur; qcur = qnxt; qnxt = q;
  }

  pool3_k<<<(NND + 31) / 32, 128, 0, stream>>>(xcur, batch, pooled);
  final_k<<<NG, 64, 0, stream>>>(pooled, gb, Wc, bc, out);
}

// Round 11
// 327.162 us; speedup vs baseline: 1.2937x; 1.1009x over previous
//
#include <hip/hip_runtime.h>
#include <math.h>

// Problem constants (fixed by the reference)
#define NND 50000   // nodes
#define LNP 50048   // padded rows: 782 * 64, guard-free gemm
#define NED 600000  // edges
#define CD  128     // channels (in = hid = 128)
#define NG  64      // graphs
#define NBLK 196    // ceil(NND/256) scan blocks
#define GROWS 64    // rows per gemm block

typedef short s8v  __attribute__((ext_vector_type(8)));   // 8 bf16 (raw bits) = 4 VGPRs
typedef float f4v  __attribute__((ext_vector_type(4)));   // MFMA accumulator
typedef float f2v  __attribute__((ext_vector_type(2)));
typedef unsigned short u16x4 __attribute__((ext_vector_type(4)));
typedef unsigned short u16x8 __attribute__((ext_vector_type(8)));

static __device__ __forceinline__ unsigned short f2bf(float f) {
  union { float f; unsigned u; } v; v.f = f;
  unsigned r = v.u + 0x7fffu + ((v.u >> 16) & 1u);   // round-to-nearest-even
  return (unsigned short)(r >> 16);
}
static __device__ __forceinline__ float bf2f(unsigned short h) {
  union { unsigned u; float f; } v; v.u = ((unsigned)h) << 16; return v.f;
}
// 4 floats -> 4 packed OCP e4m3 bytes (HW RNE+sat)
static __device__ __forceinline__ unsigned f2fp8x4(float a, float b, float c, float d) {
  int r = __builtin_amdgcn_cvt_pk_fp8_f32(a, b, 0, false);
  r = __builtin_amdgcn_cvt_pk_fp8_f32(c, d, r, true);
  return (unsigned)r;
}
// async global->LDS, 16B per lane (m97 pattern: wave-uniform LDS base + lane*16)
static __device__ __forceinline__ void g2lds(const unsigned short* g, unsigned short* l) {
  __builtin_amdgcn_global_load_lds(
      (const __attribute__((address_space(1))) unsigned*)g,
      (__attribute__((address_space(3))) unsigned*)l, 16, 0, 0);
}

// ---- int degree count (CSR) ----
__global__ void counti_k(const int* __restrict__ idx, int* __restrict__ cnt, int n) {
  int t = blockIdx.x * blockDim.x + threadIdx.x;
  if (t < n) atomicAdd(&cnt[idx[t]], 1);
}

// ---- 3-stage grid scan of cnt[NND] -> offs (exclusive), cur, offs[NND]=total ----
__global__ __launch_bounds__(256) void bsum_k(const int* __restrict__ cnt,
                                              int* __restrict__ bsum) {
  __shared__ int s[256];
  int i = blockIdx.x * 256 + threadIdx.x;
  s[threadIdx.x] = (i < NND) ? cnt[i] : 0;
  __syncthreads();
  for (int off = 128; off > 0; off >>= 1) {
    if (threadIdx.x < off) s[threadIdx.x] += s[threadIdx.x + off];
    __syncthreads();
  }
  if (threadIdx.x == 0) bsum[blockIdx.x] = s[0];
}

// also folds in graph-boundary binary search (batch is SORTED): gb[g]=lower_bound(g)
__global__ __launch_bounds__(256) void bscan_k(const int* __restrict__ bsum,
                                               int* __restrict__ boff,
                                               int* __restrict__ offs,
                                               const int* __restrict__ batch,
                                               int* __restrict__ gb) {
  __shared__ int s[256];
  int t = threadIdx.x;
  if (t <= NG) {
    int lo = 0, hi = NND;
    while (lo < hi) {
      int mid = (lo + hi) >> 1;
      if (batch[mid] < t) lo = mid + 1; else hi = mid;
    }
    gb[t] = lo;
  }
  s[t] = (t < NBLK) ? bsum[t] : 0;
  __syncthreads();
  for (int off = 1; off < 256; off <<= 1) {   // inclusive Hillis-Steele
    int v = (t >= off) ? s[t - off] : 0;
    __syncthreads();
    s[t] += v;
    __syncthreads();
  }
  if (t < NBLK) boff[t] = (t == 0) ? 0 : s[t - 1];
  if (t == NBLK - 1) offs[NND] = s[t];        // grand total
}

__global__ __launch_bounds__(256) void escan_k(const int* __restrict__ cnt,
                                               const int* __restrict__ boff,
                                               int* __restrict__ offs,
                                               int* __restrict__ cur) {
  __shared__ int s[256];
  int i = blockIdx.x * 256 + threadIdx.x;
  int t = threadIdx.x;
  int v = (i < NND) ? cnt[i] : 0;
  s[t] = v;
  __syncthreads();
  for (int off = 1; off < 256; off <<= 1) {   // inclusive Hillis-Steele
    int u = (t >= off) ? s[t - off] : 0;
    __syncthreads();
    s[t] += u;
    __syncthreads();
  }
  if (i < NND) {
    int excl = s[t] - v + boff[blockIdx.x];   // inclusive - self = exclusive
    offs[i] = excl;
    cur[i]  = excl;
  }
}

// ---- CSR fill: csr[pos] = src for edges grouped by dst ----
__global__ void fill_k(const int* __restrict__ src, const int* __restrict__ dst,
                       int* __restrict__ cur, int* __restrict__ csr) {
  int e = blockIdx.x * blockDim.x + threadIdx.x;
  if (e >= NED) return;
  int d = dst[e];
  int pos = atomicAdd(&cur[d], 1);
  csr[pos] = src[e];
}

// ---- merged preamble: x -> bf16 + fp8 (range 0) and 8 weight transposes (range 1) ----
struct WPtrs { const float* w[8]; unsigned short* wt[8]; };
__global__ void prep_k(const float* __restrict__ x, unsigned short* __restrict__ xb,
                       unsigned* __restrict__ x8, WPtrs p) {
  int t = blockIdx.x * blockDim.x + threadIdx.x;
  if (t < NND * 32) {                 // one float4 chunk per thread
    float4 v = reinterpret_cast<const float4*>(x)[t];
    u16x4 o;
    o.x = f2bf(v.x); o.y = f2bf(v.y); o.z = f2bf(v.z); o.w = f2bf(v.w);
    reinterpret_cast<u16x4*>(xb)[t] = o;
    x8[t] = f2fp8x4(v.x, v.y, v.z, v.w);
  } else {
    int u = t - NND * 32;             // 8*16384 weight elements
    if (u < 8 * CD * CD) {
      int m = u >> 14, r = u & (CD * CD - 1);
      int n = r >> 7, k = r & 127;
      p.wt[m][r] = f2bf(p.w[m][k * CD + n]);
    }
  }
}

// ---- CSR gather-reduce v3 (fp8 table): ab[n] = bf16( mean xq[csr[e]] ) ----
// 16-lane team per dst node; lane owns 8 channels = ONE 8B uint2 per edge
// (full row = 128B = one cache line). 8-edge-deep unroll for MLP. Accumulate
// fp32 via HW packed fp8->f32 converts; mean emitted bf16 for the MFMA A path.
__global__ __launch_bounds__(256) void agg_k(const unsigned* __restrict__ xq,
                                             const int* __restrict__ csr,
                                             const int* __restrict__ offs,
                                             unsigned short* __restrict__ ab) {
  const int team = (blockIdx.x * 256 + threadIdx.x) >> 4;   // == node id
  const int tl   = threadIdx.x & 15;
  const int e0 = offs[team], e1 = offs[team + 1];
  const unsigned* base = xq + tl * 2;            // 2 u32 = 8 fp8 channels
  f2v a01 = {0.f, 0.f}, a23 = {0.f, 0.f}, a45 = {0.f, 0.f}, a67 = {0.f, 0.f};
  int e = e0;
  for (; e + 8 <= e1; e += 8) {
    int s[8];
#pragma unroll
    for (int j = 0; j < 8; ++j) s[j] = csr[e + j];
    uint2 v[8];
#pragma unroll
    for (int j = 0; j < 8; ++j)
      v[j] = *reinterpret_cast<const uint2*>(base + (size_t)s[j] * 32);
#pragma unroll
    for (int j = 0; j < 8; ++j) {
      a01 += __builtin_amdgcn_cvt_pk_f32_fp8(v[j].x, false);
      a23 += __builtin_amdgcn_cvt_pk_f32_fp8(v[j].x, true);
      a45 += __builtin_amdgcn_cvt_pk_f32_fp8(v[j].y, false);
      a67 += __builtin_amdgcn_cvt_pk_f32_fp8(v[j].y, true);
    }
  }
  for (; e + 4 <= e1; e += 4) {
    int s[4];
#pragma unroll
    for (int j = 0; j < 4; ++j) s[j] = csr[e + j];
    uint2 v[4];
#pragma unroll
    for (int j = 0; j < 4; ++j)
      v[j] = *reinterpret_cast<const uint2*>(base + (size_t)s[j] * 32);
#pragma unroll
    for (int j = 0; j < 4; ++j) {
      a01 += __builtin_amdgcn_cvt_pk_f32_fp8(v[j].x, false);
      a23 += __builtin_amdgcn_cvt_pk_f32_fp8(v[j].x, true);
      a45 += __builtin_amdgcn_cvt_pk_f32_fp8(v[j].y, false);
      a67 += __builtin_amdgcn_cvt_pk_f32_fp8(v[j].y, true);
    }
  }
  for (; e < e1; ++e) {
    uint2 v = *reinterpret_cast<const uint2*>(base + (size_t)csr[e] * 32);
    a01 += __builtin_amdgcn_cvt_pk_f32_fp8(v.x, false);
    a23 += __builtin_amdgcn_cvt_pk_f32_fp8(v.x, true);
    a45 += __builtin_amdgcn_cvt_pk_f32_fp8(v.y, false);
    a67 += __builtin_amdgcn_cvt_pk_f32_fp8(v.y, true);
  }
  const float invd = 1.0f / fmaxf((float)(e1 - e0), 1.0f);
  u16x8 o;
  o[0] = f2bf(a01.x * invd); o[1] = f2bf(a01.y * invd);
  o[2] = f2bf(a23.x * invd); o[3] = f2bf(a23.y * invd);
  o[4] = f2bf(a45.x * invd); o[5] = f2bf(a45.y * invd);
  o[6] = f2bf(a67.x * invd); o[7] = f2bf(a67.y * invd);
  *reinterpret_cast<u16x8*>(ab + (size_t)team * CD + tl * 8) = o;
}

// ---- fused GEMM v3 (m97-style LDS staging):
// h = relu(ab @ Wl + xb @ Wr + bias); bf16 out + optional fp8 copy.
// GUARD-FREE (LNP padding). Per block: stage both 64x128 bf16 A-tiles (32KB)
// into LDS via global_load_lds width=16 (8 DMA instrs/thread, coalesced 1KB
// per wave-instr), overlap with register-resident B-frag loads, one barrier,
// then 4 row-iters of ds_read_b128 -> MFMA.
// MFMA 16x16x32 bf16; A: m=lane&15,k=quad*8+j; B from WT[n][k]: n=lane&15;
// C/D: col=lane&15, row=quad*4+r (m89/m91-verified).
__global__ __launch_bounds__(256) void gemm3_k(
    const unsigned short* __restrict__ ab, const unsigned short* __restrict__ xb,
    const unsigned short* __restrict__ WlT, const unsigned short* __restrict__ WrT,
    const float* __restrict__ bias, unsigned short* __restrict__ hb,
    unsigned char* __restrict__ h8) {
  __shared__ unsigned short abuf[GROWS * CD];   // 16 KB, row-major (no pad: DMA layout)
  __shared__ unsigned short xbuf[GROWS * CD];   // 16 KB

  const int tid  = threadIdx.x;
  const int wave = tid >> 6;
  const int lane = tid & 63;
  const int quad = lane >> 4;
  const int l16  = lane & 15;
  const size_t rbase = (size_t)blockIdx.x * GROWS;

  // Issue the A-tile DMA first (fire-and-forget into LDS)
#pragma unroll
  for (int j = 0; j < 4; ++j) {
    const int s = j * 256 + tid;            // 16B slot: row = s/16, chunk = s%16
    const size_t goff = (rbase + (s >> 4)) * CD + (s & 15) * 8;
    g2lds(ab + goff, &abuf[(size_t)s * 8]);
    g2lds(xb + goff, &xbuf[(size_t)s * 8]);
  }

  // B fragments -> registers (overlaps the DMA)
  s8v bL[2][4], bR[2][4];
#pragma unroll
  for (int nt = 0; nt < 2; ++nt) {
    const int n = wave * 32 + nt * 16 + l16;
#pragma unroll
    for (int kk = 0; kk < 4; ++kk) {
      size_t woff = (size_t)n * CD + kk * 32 + quad * 8;
      bL[nt][kk] = *reinterpret_cast<const s8v*>(WlT + woff);
      bR[nt][kk] = *reinterpret_cast<const s8v*>(WrT + woff);
    }
  }
  const float bv0 = bias[wave * 32 + l16];
  const float bv1 = bias[wave * 32 + 16 + l16];

  __syncthreads();   // drains DMA (vmcnt) + barrier

#pragma unroll
  for (int rt = 0; rt < GROWS / 16; ++rt) {
    const unsigned short* arow = abuf + (rt * 16 + l16) * CD + quad * 8;
    const unsigned short* xrow = xbuf + (rt * 16 + l16) * CD + quad * 8;
    f4v acc0 = {}, acc1 = {};
#pragma unroll
    for (int kk = 0; kk < 4; ++kk) {
      s8v aA = *reinterpret_cast<const s8v*>(arow + kk * 32);   // ds_read_b128
      s8v aX = *reinterpret_cast<const s8v*>(xrow + kk * 32);
      acc0 = __builtin_amdgcn_mfma_f32_16x16x32_bf16(aA, bL[0][kk], acc0, 0, 0, 0);
      acc0 = __builtin_amdgcn_mfma_f32_16x16x32_bf16(aX, bR[0][kk], acc0, 0, 0, 0);
      acc1 = __builtin_amdgcn_mfma_f32_16x16x32_bf16(aA, bL[1][kk], acc1, 0, 0, 0);
      acc1 = __builtin_amdgcn_mfma_f32_16x16x32_bf16(aX, bR[1][kk], acc1, 0, 0, 0);
    }
    const size_t row0 = rbase + rt * 16 + quad * 4;
    const int c0 = wave * 32 + l16;
#pragma unroll
    for (int r = 0; r < 4; ++r) {
      const size_t row = row0 + r;
      float v0 = fmaxf(acc0[r] + bv0, 0.0f);
      float v1 = fmaxf(acc1[r] + bv1, 0.0f);
      hb[row * CD + c0]      = f2bf(v0);
      hb[row * CD + c0 + 16] = f2bf(v1);
      if (h8) {
        int p0 = __builtin_amdgcn_cvt_pk_fp8_f32(v0, v0, 0, false);
        int p1 = __builtin_amdgcn_cvt_pk_fp8_f32(v1, v1, 0, false);
        h8[row * CD + c0]      = (unsigned char)p0;
        h8[row * CD + c0 + 16] = (unsigned char)p1;
      }
    }
  }
}

// ---- mean-pool over bf16 features: 32-row chunks, one thread per channel,
// boundary-flush atomics; batch is SORTED. ----
__global__ __launch_bounds__(128) void pool3_k(const unsigned short* __restrict__ h,
                                               const int* __restrict__ batch,
                                               float* __restrict__ pooled) {
  const int c  = threadIdx.x;
  const int r0 = blockIdx.x * 32;
  const int rend = (r0 + 32 < NND) ? r0 + 32 : NND;
  const int g0 = batch[r0];
  const int g1 = batch[rend - 1];
  if (g0 == g1) {
    float acc = 0.f;
#pragma unroll
    for (int i = 0; i < 32; ++i) {
      int row = r0 + i;
      if (row < rend) acc += bf2f(h[(size_t)row * CD + c]);
    }
    atomicAdd(&pooled[g0 * CD + c], acc);
  } else {
    float acc = 0.f;
    int gcur = g0;
    for (int row = r0; row < rend; ++row) {
      int g = batch[row];
      if (g != gcur) {
        atomicAdd(&pooled[gcur * CD + c], acc);
        acc = 0.f; gcur = g;
      }
      acc += bf2f(h[(size_t)row * CD + c]);
    }
    atomicAdd(&pooled[gcur * CD + c], acc);
  }
}

// ---- classifier: out[g] = sigmoid(dot(pooled[g]/cnt, Wc) + bc) ----
__global__ void final_k(const float* __restrict__ pooled, const int* __restrict__ gb,
                        const float* __restrict__ Wc, const float* __restrict__ bc,
                        float* __restrict__ out) {
  int g = blockIdx.x;
  int lane = threadIdx.x;
  float part = pooled[g * CD + lane] * Wc[lane] +
               pooled[g * CD + 64 + lane] * Wc[64 + lane];
#pragma unroll
  for (int off = 32; off > 0; off >>= 1) part += __shfl_down(part, off, 64);
  if (lane == 0) {
    float cnt = (float)(gb[g + 1] - gb[g]);
    float z = part / fmaxf(cnt, 1.0f) + bc[0];
    out[g] = 1.0f / (1.0f + expf(-z));
  }
}

extern "C" void kernel_launch(void* const* d_in, const int* in_sizes, int n_in,
                              void* d_out, int out_size, void* d_ws, size_t ws_size,
                              hipStream_t stream) {
  const float* x   = (const float*)d_in[0];
  const int*   ei  = (const int*)d_in[1];
  const int*   src = ei;             // edge_index[0]
  const int*   dst = ei + NED;       // edge_index[1]
  // d_in[2] = edge_weight: unused by the reference
  const int*   batch = (const int*)d_in[3];
  const float* Wc = (const float*)d_in[16];
  const float* bc = (const float*)d_in[17];
  float* out = (float*)d_out;

  char* w = (char*)d_ws;
  auto alloc = [&](size_t bytes) {
    char* p = w; w += (bytes + 255) & ~(size_t)255; return p;
  };
  // cnti + pooled first and contiguous: one memset covers both
  int* cnti = (int*)alloc(NND * 4);
  float* pooled = (float*)alloc(NG * CD * 4);
  size_t zspan = (size_t)(w - (char*)cnti);
  int* offs = (int*)alloc((NND + 1) * 4);
  int* cur  = (int*)alloc(NND * 4);
  int* csr  = (int*)alloc((size_t)NED * 4);
  int* gb   = (int*)alloc((NG + 1) * 4);
  int* bsum = (int*)alloc(256 * 4);
  int* boff = (int*)alloc(256 * 4);
  unsigned short* xb0 = (unsigned short*)alloc((size_t)LNP * CD * 2);
  unsigned short* xb1 = (unsigned short*)alloc((size_t)LNP * CD * 2);
  unsigned short* ab  = (unsigned short*)alloc((size_t)LNP * CD * 2);
  unsigned char* x8a = (unsigned char*)alloc((size_t)LNP * CD);
  unsigned char* x8b = (unsigned char*)alloc((size_t)LNP * CD);
  WPtrs wp;
  for (int i = 0; i < 4; ++i) {
    wp.w[2 * i]     = (const float*)d_in[4 + 3 * i];      // Wl{i+1}
    wp.w[2 * i + 1] = (const float*)d_in[5 + 3 * i];      // Wr{i+1}
  }
  for (int i = 0; i < 8; ++i) wp.wt[i] = (unsigned short*)alloc(CD * CD * 2);
  const float* bs[4] = {(const float*)d_in[6],  (const float*)d_in[9],
                        (const float*)d_in[12], (const float*)d_in[15]};

  hipMemsetAsync(cnti, 0, zspan, stream);

  // CSR build (per call; inputs are restored before every timed launch)
  counti_k<<<(NED + 255) / 256, 256, 0, stream>>>(dst, cnti, NED);
  bsum_k<<<NBLK, 256, 0, stream>>>(cnti, bsum);
  bscan_k<<<1, 256, 0, stream>>>(bsum, boff, offs, batch, gb);
  escan_k<<<NBLK, 256, 0, stream>>>(cnti, boff, offs, cur);
  fill_k<<<(NED + 255) / 256, 256, 0, stream>>>(src, dst, cur, csr);

  prep_k<<<(NND * 32 + 8 * CD * CD + 255) / 256, 256, 0, stream>>>(
      x, xb0, (unsigned*)x8a, wp);

  unsigned short* xcur = xb0;
  unsigned short* xnxt = xb1;
  unsigned char* qcur = x8a;
  unsigned char* qnxt = x8b;
  const int ggrid = LNP / GROWS;   // 782, guard-free
  for (int l = 0; l < 4; ++l) {
    agg_k<<<NND * 16 / 256, 256, 0, stream>>>((const unsigned*)qcur, csr, offs, ab);
    gemm3_k<<<ggrid, 256, 0, stream>>>(ab, xcur, wp.wt[2 * l], wp.wt[2 * l + 1],
                                       bs[l], xnxt, (l < 3) ? qnxt : nullptr);
    unsigned short* t = xcur; xcur = xnxt; xnxt = t;
    unsigned char* q = qcur; qcur = qnxt; qnxt = q;
  }

  pool3_k<<<(NND + 31) / 32, 128, 0, stream>>>(xcur, batch, pooled);
  final_k<<<NG, 64, 0, stream>>>(pooled, gb, Wc, bc, out);
}